// Round 4
// baseline (532.907 us; speedup 1.0000x reference)
//
#include <hip/hip_runtime.h>
#include <hip/hip_bf16.h>
#include <stdint.h>

typedef __bf16 bf16;
typedef __attribute__((ext_vector_type(4))) __bf16 bf16x4;
typedef __attribute__((ext_vector_type(8))) __bf16 bf16x8;
typedef __attribute__((ext_vector_type(4))) float f32x4;

#define MFMA16(a, b, c) __builtin_amdgcn_mfma_f32_16x16x32_bf16((a), (b), (c), 0, 0, 0)

__device__ __forceinline__ void async_cp16(const bf16* g, bf16* l) {
  __builtin_amdgcn_global_load_lds(
      (const __attribute__((address_space(1))) void*)g,
      (__attribute__((address_space(3))) void*)l, 16, 0, 0);
}

// ---------- fp32 -> bf16 elementwise cast (x), vectorized ----------
__global__ __launch_bounds__(256) void convx_k(const float* __restrict__ in,
                                               bf16* __restrict__ out, int n) {
  int i = (blockIdx.x * 256 + threadIdx.x) * 4;
  const int stride = gridDim.x * 256 * 4;
  for (; i < n; i += stride) {
    const f32x4 f = *(const f32x4*)(in + i);
    bf16x4 o;
    o[0] = (bf16)f[0]; o[1] = (bf16)f[1]; o[2] = (bf16)f[2]; o[3] = (bf16)f[3];
    *(bf16x4*)(out + i) = o;
  }
}

// ---------- transpose fp32 (R x C) -> bf16 (C x R), 64x64 tiles ----------
__global__ __launch_bounds__(256) void transpose_k(const float* __restrict__ in,
                                                   bf16* __restrict__ out, int R, int C) {
  __shared__ bf16 t[64][65];
  const int bc = blockIdx.x * 64;
  const int br = blockIdx.y * 64;
  const int tx = threadIdx.x & 63, ty = threadIdx.x >> 6;
#pragma unroll
  for (int r = ty; r < 64; r += 4) t[r][tx] = (bf16)in[(br + r) * C + bc + tx];
  __syncthreads();
#pragma unroll
  for (int r = ty; r < 64; r += 4) out[(bc + r) * R + br + tx] = t[tx][r];
}

// ---------------- 128x128 bf16 GEMM, BK=32, BT is N-major (N x K) ----------------
// MODE 0: fp32 store to C (M x N). MODE 1: qkv epilogue with RoPE + scatter (bf16).
template <int MODE>
__global__ __launch_bounds__(256) void gemm128(
    const bf16* __restrict__ A, const bf16* __restrict__ BT, int M, int N, int K,
    float* __restrict__ C, bf16* __restrict__ qws, bf16* __restrict__ kws,
    bf16* __restrict__ vT, const float* __restrict__ ropeC, const float* __restrict__ ropeS) {
  __shared__ __align__(16) bf16 As[128 * 32];
  __shared__ __align__(16) bf16 Bs[128 * 32];
  const int tid = threadIdx.x;
  const int lane = tid & 63, wave = tid >> 6;
  const int l16 = lane & 15, quad = lane >> 4;
  const int wm = (wave >> 1) * 64, wn = (wave & 1) * 64;
  const int bm = blockIdx.y, bn = blockIdx.x;

  const bf16* ag = A + (bm * 128 + (tid >> 2)) * K + (tid & 3) * 8;
  const bf16* bg = BT + (bn * 128 + (tid >> 2)) * K + (tid & 3) * 8;
  bf16* la = &As[tid * 8];
  bf16* lb = &Bs[tid * 8];

  f32x4 acc[4][4] = {};

  for (int k0 = 0; k0 < K; k0 += 32) {
    async_cp16(ag + k0, la);
    async_cp16(ag + 64 * K + k0, la + 2048);
    async_cp16(bg + k0, lb);
    async_cp16(bg + 64 * K + k0, lb + 2048);
    __syncthreads();
    bf16x8 af[4], bff[4];
#pragma unroll
    for (int t = 0; t < 4; ++t) {
      af[t] = *(const bf16x8*)&As[(wm + t * 16 + l16) * 32 + quad * 8];
      bff[t] = *(const bf16x8*)&Bs[(wn + t * 16 + l16) * 32 + quad * 8];
    }
#pragma unroll
    for (int mt = 0; mt < 4; ++mt)
#pragma unroll
      for (int nt = 0; nt < 4; ++nt) acc[mt][nt] = MFMA16(af[mt], bff[nt], acc[mt][nt]);
    __syncthreads();
  }

  if (MODE == 0) {
#pragma unroll
    for (int mt = 0; mt < 4; ++mt)
#pragma unroll
      for (int i = 0; i < 4; ++i) {
        const int row = bm * 128 + wm + mt * 16 + quad * 4 + i;
#pragma unroll
        for (int nt = 0; nt < 4; ++nt) {
          const int col = bn * 128 + wn + nt * 16 + l16;
          C[row * N + col] = acc[mt][nt][i];
        }
      }
  } else {
    // row = b*S + s (S=2048); col: [0,1024)=q, [1024,2048)=k, [2048,3072)=v
#pragma unroll
    for (int mt = 0; mt < 4; ++mt)
#pragma unroll
      for (int i = 0; i < 4; ++i) {
        const int row = bm * 128 + wm + mt * 16 + quad * 4 + i;
        const int b = row >> 11, s = row & 2047;
#pragma unroll
        for (int nt = 0; nt < 4; ++nt) {
          const int col = bn * 128 + wn + nt * 16 + l16;
          float v = acc[mt][nt][i];
          float p = __shfl_xor(v, 1);  // partner dim (col^1) — executed by all lanes
          const int sec = col >> 10;
          const int rem = col & 1023;
          const int h = rem >> 6, d = rem & 63;
          if (sec < 2) {  // q or k: RoPE
            float rot = (d & 1) ? p : -p;
            float cs = ropeC[s * 64 + d];
            float sn = ropeS[s * 64 + d];
            float rv = v * cs + rot * sn;
            bf16* dst = (sec == 0) ? qws : kws;
            dst[((b * 16 + h) * 2048 + s) * 64 + d] = (bf16)rv;
          } else {  // v: store transposed (b,h,d,s)
            vT[((b * 16 + h) * 64 + d) * 2048 + s] = (bf16)v;
          }
        }
      }
  }
}

// ---------------- dual-triangle flash attention ----------------
// grid: 1024 blocks = 32 (b,h) * 32 Q-tiles(64 rows); 4 waves, wave owns 16 rows.
// P transpose slab: 16 rows x 64 cols, row stride 72 elems (144 B = 9*16 B:
// bf16x8 reads stay 16B-aligned; 2-way bank alias only, free per m136).
#define PSTRIDE 72
__global__ __launch_bounds__(256) void attn_k(const bf16* __restrict__ qws,
                                              const bf16* __restrict__ kws,
                                              const bf16* __restrict__ vT,
                                              bf16* __restrict__ aw) {
  __shared__ __align__(16) bf16 plds[4][16 * PSTRIDE];
  const int tid = threadIdx.x;
  const int lane = tid & 63, wave = tid >> 6;
  const int l16 = lane & 15, quad = lane >> 4;
  const int bh = blockIdx.x >> 5, qt = blockIdx.x & 31;
  const int b = bh >> 4, h = bh & 15;
  const int i0 = qt * 64 + wave * 16;

  const bf16* qbase = qws + (bh * 2048 + i0) * 64;
  const bf16x8 qfu = *(const bf16x8*)(qbase + l16 * 64 + quad * 8);
  const bf16x8 qfd = *(const bf16x8*)(qbase + l16 * 64 + 32 + quad * 8);
  const bf16* kbase = kws + bh * 2048 * 64;
  const bf16* vbase = vT + bh * 64 * 2048;
  bf16* pw = &plds[wave][0];

  f32x4 o[4] = {};
  float m_r[4] = {-1e30f, -1e30f, -1e30f, -1e30f};
  float l_r[4] = {0.f, 0.f, 0.f, 0.f};
  const float sc = 0.17677669529663687f * 1.4426950408889634f;  // scale * log2(e)

  for (int jt = 0; jt < 32; ++jt) {
    const int j0 = jt * 64;
    f32x4 zz = {};
    f32x4 su[4], sd[4];
#pragma unroll
    for (int nt = 0; nt < 4; ++nt) {
      const bf16* kp = kbase + (j0 + nt * 16 + l16) * 64 + quad * 8;
      bf16x8 kfu = *(const bf16x8*)kp;
      bf16x8 kfd = *(const bf16x8*)(kp + 32);
      su[nt] = MFMA16(qfu, kfu, zz);
      sd[nt] = MFMA16(qfd, kfd, zz);
    }
    float s[4][4];
    float tmax[4] = {-1e30f, -1e30f, -1e30f, -1e30f};
#pragma unroll
    for (int nt = 0; nt < 4; ++nt) {
      const int col = j0 + nt * 16 + l16;
#pragma unroll
      for (int i = 0; i < 4; ++i) {
        const int row = i0 + quad * 4 + i;
        float x = (col <= row ? sd[nt][i] : su[nt][i]) * sc;  // tril -> down, else up
        s[nt][i] = x;
        tmax[i] = fmaxf(tmax[i], x);
      }
    }
#pragma unroll
    for (int off = 1; off < 16; off <<= 1)
#pragma unroll
      for (int i = 0; i < 4; ++i) tmax[i] = fmaxf(tmax[i], __shfl_xor(tmax[i], off));
    float alpha[4], rsum[4] = {0.f, 0.f, 0.f, 0.f};
#pragma unroll
    for (int i = 0; i < 4; ++i) {
      float mn = fmaxf(m_r[i], tmax[i]);
      alpha[i] = exp2f(m_r[i] - mn);
      m_r[i] = mn;
    }
#pragma unroll
    for (int nt = 0; nt < 4; ++nt)
#pragma unroll
      for (int i = 0; i < 4; ++i) {
        float p = exp2f(s[nt][i] - m_r[i]);
        s[nt][i] = p;
        rsum[i] += p;
      }
#pragma unroll
    for (int off = 1; off < 16; off <<= 1)
#pragma unroll
      for (int i = 0; i < 4; ++i) rsum[i] += __shfl_xor(rsum[i], off);
#pragma unroll
    for (int i = 0; i < 4; ++i) l_r[i] = l_r[i] * alpha[i] + rsum[i];
#pragma unroll
    for (int nt = 0; nt < 4; ++nt)
#pragma unroll
      for (int i = 0; i < 4; ++i) o[nt][i] *= alpha[i];
    // P: C-layout -> LDS -> A-layout
#pragma unroll
    for (int nt = 0; nt < 4; ++nt)
#pragma unroll
      for (int i = 0; i < 4; ++i)
        pw[(quad * 4 + i) * PSTRIDE + nt * 16 + l16] = (bf16)s[nt][i];
    __syncthreads();
#pragma unroll
    for (int ks = 0; ks < 2; ++ks) {
      bf16x8 pf = *(const bf16x8*)&pw[l16 * PSTRIDE + ks * 32 + quad * 8];
#pragma unroll
      for (int nt = 0; nt < 4; ++nt) {
        bf16x8 vf = *(const bf16x8*)(vbase + (nt * 16 + l16) * 2048 + j0 + ks * 32 + quad * 8);
        o[nt] = MFMA16(pf, vf, o[nt]);
      }
    }
    __syncthreads();
  }
#pragma unroll
  for (int i = 0; i < 4; ++i) {
    const int row = i0 + quad * 4 + i;
    const float rl = 1.0f / l_r[i];
#pragma unroll
    for (int nt = 0; nt < 4; ++nt)
      aw[(b * 2048 + row) * 1024 + h * 64 + nt * 16 + l16] = (bf16)(o[nt][i] * rl);
  }
}

extern "C" void kernel_launch(void* const* d_in, const int* in_sizes, int n_in,
                              void* d_out, int out_size, void* d_ws, size_t ws_size,
                              hipStream_t stream) {
  const float* x = (const float*)d_in[0];       // (2,2048,1024) fp32
  const float* w_qkv = (const float*)d_in[1];   // (1024,3072) fp32
  const float* w_proj = (const float*)d_in[2];  // (1024,1024) fp32
  const float* ropeC = (const float*)d_in[3];   // (2048,64) fp32
  const float* ropeS = (const float*)d_in[4];   // (2048,64) fp32
  float* out = (float*)d_out;                   // (2,2048,1024) fp32

  char* ws = (char*)d_ws;
  bf16* xb = (bf16*)ws;     ws += (size_t)4194304 * 2;  // (4096,1024) bf16
  bf16* wqkvT = (bf16*)ws;  ws += (size_t)3145728 * 2;  // (3072,1024) N-major bf16
  bf16* wprojT = (bf16*)ws; ws += (size_t)1048576 * 2;  // (1024,1024) N-major bf16
  bf16* qws = (bf16*)ws;    ws += (size_t)4194304 * 2;  // (2,16,2048,64)
  bf16* kws = (bf16*)ws;    ws += (size_t)4194304 * 2;  // (2,16,2048,64)
  bf16* vT = (bf16*)ws;     ws += (size_t)4194304 * 2;  // (2,16,64,2048)
  bf16* aw = (bf16*)ws;     ws += (size_t)4194304 * 2;  // (4096,1024)

  convx_k<<<1024, 256, 0, stream>>>(x, xb, 4194304);
  transpose_k<<<dim3(3072 / 64, 1024 / 64), 256, 0, stream>>>(w_qkv, wqkvT, 1024, 3072);
  transpose_k<<<dim3(1024 / 64, 1024 / 64), 256, 0, stream>>>(w_proj, wprojT, 1024, 1024);

  gemm128<1><<<dim3(3072 / 128, 4096 / 128), 256, 0, stream>>>(
      xb, wqkvT, 4096, 3072, 1024, nullptr, qws, kws, vT, ropeC, ropeS);
  attn_k<<<1024, 256, 0, stream>>>(qws, kws, vT, aw);
  gemm128<0><<<dim3(1024 / 128, 4096 / 128), 256, 0, stream>>>(
      aw, wprojT, 4096, 1024, 1024, out, nullptr, nullptr, nullptr, nullptr, nullptr);
}

// Round 5
// 275.021 us; speedup vs baseline: 1.9377x; 1.9377x over previous
//
#include <hip/hip_runtime.h>
#include <hip/hip_bf16.h>
#include <stdint.h>

typedef __bf16 bf16;
typedef __attribute__((ext_vector_type(4))) __bf16 bf16x4;
typedef __attribute__((ext_vector_type(8))) __bf16 bf16x8;
typedef __attribute__((ext_vector_type(4))) float f32x4;

#define MFMA16(a, b, c) __builtin_amdgcn_mfma_f32_16x16x32_bf16((a), (b), (c), 0, 0, 0)

__device__ __forceinline__ void async_cp16(const bf16* g, bf16* l) {
  __builtin_amdgcn_global_load_lds(
      (const __attribute__((address_space(1))) void*)g,
      (__attribute__((address_space(3))) void*)l, 16, 0, 0);
}

// ---------- fp32 -> bf16 elementwise cast (x), vectorized ----------
__global__ __launch_bounds__(256) void convx_k(const float* __restrict__ in,
                                               bf16* __restrict__ out, int n) {
  int i = (blockIdx.x * 256 + threadIdx.x) * 4;
  const int stride = gridDim.x * 256 * 4;
  for (; i < n; i += stride) {
    const f32x4 f = *(const f32x4*)(in + i);
    bf16x4 o;
    o[0] = (bf16)f[0]; o[1] = (bf16)f[1]; o[2] = (bf16)f[2]; o[3] = (bf16)f[3];
    *(bf16x4*)(out + i) = o;
  }
}

// ---------- transpose fp32 (R x C) -> bf16 (C x R), 64x64 tiles ----------
__global__ __launch_bounds__(256) void transpose_k(const float* __restrict__ in,
                                                   bf16* __restrict__ out, int R, int C) {
  __shared__ bf16 t[64][65];
  const int bc = blockIdx.x * 64;
  const int br = blockIdx.y * 64;
  const int tx = threadIdx.x & 63, ty = threadIdx.x >> 6;
#pragma unroll
  for (int r = ty; r < 64; r += 4) t[r][tx] = (bf16)in[(br + r) * C + bc + tx];
  __syncthreads();
#pragma unroll
  for (int r = ty; r < 64; r += 4) out[(bc + r) * R + br + tx] = t[tx][r];
}

// ---------------- BMx128 bf16 GEMM, BK=32, BT is N-major (N x K) ----------------
// MODE 0: fp32 store to C. MODE 1: qkv epilogue with RoPE + scatter (bf16).
template <int MODE, int BM>
__global__ __launch_bounds__(256) void gemm128(
    const bf16* __restrict__ A, const bf16* __restrict__ BT, int M, int N, int K,
    float* __restrict__ C, bf16* __restrict__ qws, bf16* __restrict__ kws,
    bf16* __restrict__ vT, const float* __restrict__ ropeC, const float* __restrict__ ropeS) {
  constexpr int MT = BM / 32;  // 16-row tiles per wave
  __shared__ __align__(16) bf16 As[BM * 32];
  __shared__ __align__(16) bf16 Bs[128 * 32];
  const int tid = threadIdx.x;
  const int lane = tid & 63, wave = tid >> 6;
  const int l16 = lane & 15, quad = lane >> 4;
  const int wm = (wave >> 1) * (BM / 2), wn = (wave & 1) * 64;
  const int bm = blockIdx.y, bn = blockIdx.x;

  const bf16* ag = A + (bm * BM + (tid >> 2)) * K + (tid & 3) * 8;
  const bf16* bg = BT + (bn * 128 + (tid >> 2)) * K + (tid & 3) * 8;
  bf16* la = &As[tid * 8];
  bf16* lb = &Bs[tid * 8];

  f32x4 acc[MT][4] = {};

  for (int k0 = 0; k0 < K; k0 += 32) {
    async_cp16(ag + k0, la);
    if (BM == 128) async_cp16(ag + 64 * K + k0, la + 2048);
    async_cp16(bg + k0, lb);
    async_cp16(bg + 64 * K + k0, lb + 2048);
    __syncthreads();
    bf16x8 af[MT], bff[4];
#pragma unroll
    for (int t = 0; t < MT; ++t)
      af[t] = *(const bf16x8*)&As[(wm + t * 16 + l16) * 32 + quad * 8];
#pragma unroll
    for (int t = 0; t < 4; ++t)
      bff[t] = *(const bf16x8*)&Bs[(wn + t * 16 + l16) * 32 + quad * 8];
#pragma unroll
    for (int mt = 0; mt < MT; ++mt)
#pragma unroll
      for (int nt = 0; nt < 4; ++nt) acc[mt][nt] = MFMA16(af[mt], bff[nt], acc[mt][nt]);
    __syncthreads();
  }

  if (MODE == 0) {
#pragma unroll
    for (int mt = 0; mt < MT; ++mt)
#pragma unroll
      for (int i = 0; i < 4; ++i) {
        const int row = bm * BM + wm + mt * 16 + quad * 4 + i;
#pragma unroll
        for (int nt = 0; nt < 4; ++nt) {
          const int col = bn * 128 + wn + nt * 16 + l16;
          C[row * N + col] = acc[mt][nt][i];
        }
      }
  } else {
    // per-wave LDS bounce buffer (reuses Bs; safe after final barrier above)
    bf16* tb = &Bs[wave * 512];  // 16 x 16 tile, stride 20 (conflict-free)
#pragma unroll
    for (int mt = 0; mt < MT; ++mt) {
      const int s0 = bm * BM + wm + mt * 16;  // = b*2048 + sbase, 16-aligned
      const int b = s0 >> 11, sbase = s0 & 2047;
#pragma unroll
      for (int nt = 0; nt < 4; ++nt) {
        const int colb = bn * 128 + wn + nt * 16;
        const int sec = colb >> 10, rem = colb & 1023;
        const int h = rem >> 6, d0 = rem & 63;
        if (sec < 2) {  // q or k: RoPE, bounce through LDS for b64 stores
          const int d = d0 + l16;
#pragma unroll
          for (int i = 0; i < 4; ++i) {
            const int s = sbase + quad * 4 + i;
            float v = acc[mt][nt][i];
            float pr = __shfl_xor(v, 1);  // partner dim d^1 (lane l16^1)
            float rot = (d & 1) ? pr : -pr;
            float rv = v * ropeC[s * 64 + d] + rot * ropeS[s * 64 + d];
            tb[(quad * 4 + i) * 20 + l16] = (bf16)rv;
          }
          bf16* dst = ((sec == 0) ? qws : kws) + ((b * 16 + h) * 2048 + sbase) * 64 + d0;
          bf16x4 seg = *(const bf16x4*)&tb[l16 * 20 + quad * 4];
          *(bf16x4*)(dst + l16 * 64 + quad * 4) = seg;
        } else {  // v: pack 4 consecutive s at fixed d, store b64 to vT (d-major)
          const int d = d0 + l16;
          bf16x4 pk;
#pragma unroll
          for (int i = 0; i < 4; ++i) pk[i] = (bf16)acc[mt][nt][i];
          *(bf16x4*)(vT + ((b * 16 + h) * 64 + d) * 2048 + sbase + quad * 4) = pk;
        }
      }
    }
  }
}

// ---------------- dual-triangle attention, single-pass (no max), split-K ----------------
// grid: 2048 blocks = 32 (b,h) * 64 Q-tiles(32 rows). 4 waves: wave w owns K-cols
// [w*512, w*512+512) for the SAME 32 rows. No in-loop barriers. S computed as S^T
// (A=K, B=Q) so each lane owns one Q-row: per-lane l accumulation, b64 P writes.
__global__ __launch_bounds__(256) void attn_k(const bf16* __restrict__ qws,
                                              const bf16* __restrict__ kws,
                                              const bf16* __restrict__ vT,
                                              bf16* __restrict__ aw) {
  __shared__ __align__(16) char smem[33280];  // P: 4*32*72*2=18432 | merge: 4*32*64*4+512
  const int tid = threadIdx.x;
  const int lane = tid & 63, wave = tid >> 6;
  const int l16 = lane & 15, quad = lane >> 4;
  const int bh = blockIdx.x >> 6, qt = blockIdx.x & 63;
  const int b = bh >> 4, h = bh & 15;
  const int i0 = qt * 32;

  const bf16* qb = qws + (bh * 2048 + i0) * 64;
  const bf16* kbase = kws + bh * 2048 * 64;
  const bf16* vbase = vT + bh * 64 * 2048;
  bf16* pw = (bf16*)smem + wave * (32 * 72);

  bf16x8 qf[2][2];
#pragma unroll
  for (int mt = 0; mt < 2; ++mt)
#pragma unroll
    for (int hf = 0; hf < 2; ++hf)
      qf[mt][hf] = *(const bf16x8*)(qb + (mt * 16 + l16) * 64 + hf * 32 + quad * 8);

  f32x4 o[2][4] = {};
  float lp[2] = {0.f, 0.f};
  const float sc = 0.17677669529663687f * 1.4426950408889634f;  // scale * log2(e)
  const f32x4 zz = {};

  for (int jt = 0; jt < 8; ++jt) {
    const int j0 = wave * 512 + jt * 64;
    bf16x8 vf[2][4];
#pragma unroll
    for (int ks = 0; ks < 2; ++ks)
#pragma unroll
      for (int nt = 0; nt < 4; ++nt)
        vf[ks][nt] = *(const bf16x8*)(vbase + (nt * 16 + l16) * 2048 + j0 + ks * 32 + quad * 8);
#pragma unroll
    for (int nt = 0; nt < 4; ++nt) {
      const bf16* kp = kbase + (j0 + nt * 16 + l16) * 64 + quad * 8;
      bf16x8 kfu = *(const bf16x8*)kp;
      bf16x8 kfd = *(const bf16x8*)(kp + 32);
      f32x4 su[2], sd[2];
#pragma unroll
      for (int mt = 0; mt < 2; ++mt) {
        su[mt] = MFMA16(kfu, qf[mt][0], zz);  // S^T: row=K-col, col=Q-row
        sd[mt] = MFMA16(kfd, qf[mt][1], zz);
      }
#pragma unroll
      for (int mt = 0; mt < 2; ++mt) {
        const int irow = i0 + mt * 16 + l16;
        bf16x4 pk;
        float ls = 0.f;
#pragma unroll
        for (int r = 0; r < 4; ++r) {
          const int jcol = j0 + nt * 16 + quad * 4 + r;
          float x = ((jcol <= irow) ? sd[mt][r] : su[mt][r]) * sc;  // tril->down
          float pe = exp2f(x);
          ls += pe;
          pk[r] = (bf16)pe;
        }
        lp[mt] += ls;
        *(bf16x4*)(pw + (mt * 16 + l16) * 72 + nt * 16 + quad * 4) = pk;
      }
    }
#pragma unroll
    for (int mt = 0; mt < 2; ++mt)
#pragma unroll
      for (int ks = 0; ks < 2; ++ks) {
        bf16x8 pf = *(const bf16x8*)(pw + (mt * 16 + l16) * 72 + ks * 32 + quad * 8);
#pragma unroll
        for (int nt = 0; nt < 4; ++nt) o[mt][nt] = MFMA16(pf, vf[ks][nt], o[mt][nt]);
      }
  }
  // per-row l: 4 quads hold complementary partials of the same row
#pragma unroll
  for (int mt = 0; mt < 2; ++mt) {
    lp[mt] += __shfl_xor(lp[mt], 16);
    lp[mt] += __shfl_xor(lp[mt], 32);
  }
  __syncthreads();  // all waves done with P region before aliasing as merge space
  float* oL = (float*)smem;             // [4][32][64]
  float* lL = (float*)(smem + 32768);   // [4][32]
#pragma unroll
  for (int mt = 0; mt < 2; ++mt) {
#pragma unroll
    for (int nt = 0; nt < 4; ++nt)
#pragma unroll
      for (int r = 0; r < 4; ++r)
        oL[wave * 2048 + (mt * 16 + quad * 4 + r) * 64 + nt * 16 + l16] = o[mt][nt][r];
    if (quad == 0) lL[wave * 32 + mt * 16 + l16] = lp[mt];
  }
  __syncthreads();
  const int c = tid & 63, w2 = tid >> 6;
#pragma unroll
  for (int rr = 0; rr < 8; ++rr) {
    const int r = w2 * 8 + rr;
    float s4 = oL[r * 64 + c] + oL[2048 + r * 64 + c] + oL[4096 + r * 64 + c] +
               oL[6144 + r * 64 + c];
    float ls = lL[r] + lL[32 + r] + lL[64 + r] + lL[96 + r];
    aw[(b * 2048 + i0 + r) * 1024 + h * 64 + c] = (bf16)(s4 / ls);
  }
}

extern "C" void kernel_launch(void* const* d_in, const int* in_sizes, int n_in,
                              void* d_out, int out_size, void* d_ws, size_t ws_size,
                              hipStream_t stream) {
  const float* x = (const float*)d_in[0];       // (2,2048,1024) fp32
  const float* w_qkv = (const float*)d_in[1];   // (1024,3072) fp32
  const float* w_proj = (const float*)d_in[2];  // (1024,1024) fp32
  const float* ropeC = (const float*)d_in[3];   // (2048,64) fp32
  const float* ropeS = (const float*)d_in[4];   // (2048,64) fp32
  float* out = (float*)d_out;                   // (2,2048,1024) fp32

  char* ws = (char*)d_ws;
  bf16* xb = (bf16*)ws;     ws += (size_t)4194304 * 2;  // (4096,1024) bf16
  bf16* wqkvT = (bf16*)ws;  ws += (size_t)3145728 * 2;  // (3072,1024) N-major bf16
  bf16* wprojT = (bf16*)ws; ws += (size_t)1048576 * 2;  // (1024,1024) N-major bf16
  bf16* qws = (bf16*)ws;    ws += (size_t)4194304 * 2;  // (2,16,2048,64)
  bf16* kws = (bf16*)ws;    ws += (size_t)4194304 * 2;  // (2,16,2048,64)
  bf16* vT = (bf16*)ws;     ws += (size_t)4194304 * 2;  // (2,16,64,2048)
  bf16* aw = (bf16*)ws;     ws += (size_t)4194304 * 2;  // (4096,1024)

  convx_k<<<1024, 256, 0, stream>>>(x, xb, 4194304);
  transpose_k<<<dim3(3072 / 64, 1024 / 64), 256, 0, stream>>>(w_qkv, wqkvT, 1024, 3072);
  transpose_k<<<dim3(1024 / 64, 1024 / 64), 256, 0, stream>>>(w_proj, wprojT, 1024, 1024);

  gemm128<1, 128><<<dim3(3072 / 128, 4096 / 128), 256, 0, stream>>>(
      xb, wqkvT, 4096, 3072, 1024, nullptr, qws, kws, vT, ropeC, ropeS);
  attn_k<<<2048, 256, 0, stream>>>(qws, kws, vT, aw);
  gemm128<0, 64><<<dim3(1024 / 128, 4096 / 64), 256, 0, stream>>>(
      aw, wprojT, 4096, 1024, 1024, out, nullptr, nullptr, nullptr, nullptr, nullptr);
}

// Round 6
// 264.891 us; speedup vs baseline: 2.0118x; 1.0382x over previous
//
#include <hip/hip_runtime.h>
#include <hip/hip_bf16.h>
#include <stdint.h>

typedef __bf16 bf16;
typedef __attribute__((ext_vector_type(4))) __bf16 bf16x4;
typedef __attribute__((ext_vector_type(8))) __bf16 bf16x8;
typedef __attribute__((ext_vector_type(4))) float f32x4;

#define MFMA16(a, b, c) __builtin_amdgcn_mfma_f32_16x16x32_bf16((a), (b), (c), 0, 0, 0)

// scale (1/sqrt(32)) * log2(e), folded into q at the gemm1 epilogue
#define QSC (0.17677669529663687f * 1.4426950408889634f)

__device__ __forceinline__ void async_cp16(const bf16* g, bf16* l) {
  __builtin_amdgcn_global_load_lds(
      (const __attribute__((address_space(1))) void*)g,
      (__attribute__((address_space(3))) void*)l, 16, 0, 0);
}

// ---------- fp32 -> bf16 elementwise cast (x), vectorized ----------
__global__ __launch_bounds__(256) void convx_k(const float* __restrict__ in,
                                               bf16* __restrict__ out, int n) {
  int i = (blockIdx.x * 256 + threadIdx.x) * 4;
  const int stride = gridDim.x * 256 * 4;
  for (; i < n; i += stride) {
    const f32x4 f = *(const f32x4*)(in + i);
    bf16x4 o;
    o[0] = (bf16)f[0]; o[1] = (bf16)f[1]; o[2] = (bf16)f[2]; o[3] = (bf16)f[3];
    *(bf16x4*)(out + i) = o;
  }
}

// ---------- transpose fp32 (R x C) -> bf16 (C x R), 64x64 tiles ----------
__global__ __launch_bounds__(256) void transpose_k(const float* __restrict__ in,
                                                   bf16* __restrict__ out, int R, int C) {
  __shared__ bf16 t[64][65];
  const int bc = blockIdx.x * 64;
  const int br = blockIdx.y * 64;
  const int tx = threadIdx.x & 63, ty = threadIdx.x >> 6;
#pragma unroll
  for (int r = ty; r < 64; r += 4) t[r][tx] = (bf16)in[(br + r) * C + bc + tx];
  __syncthreads();
#pragma unroll
  for (int r = ty; r < 64; r += 4) out[(bc + r) * R + br + tx] = t[tx][r];
}

// ---------------- BMx128 bf16 GEMM, BK=32, BT is N-major (N x K) ----------------
// MODE 0: fp32 store to C. MODE 1: qkv epilogue with RoPE + scatter (bf16).
template <int MODE, int BM>
__global__ __launch_bounds__(256) void gemm128(
    const bf16* __restrict__ A, const bf16* __restrict__ BT, int M, int N, int K,
    float* __restrict__ C, bf16* __restrict__ qws, bf16* __restrict__ kws,
    bf16* __restrict__ vT, const float* __restrict__ ropeC, const float* __restrict__ ropeS) {
  constexpr int MT = BM / 32;  // 16-row tiles per wave
  __shared__ __align__(16) bf16 As[BM * 32];
  __shared__ __align__(16) bf16 Bs[128 * 32];
  const int tid = threadIdx.x;
  const int lane = tid & 63, wave = tid >> 6;
  const int l16 = lane & 15, quad = lane >> 4;
  const int wm = (wave >> 1) * (BM / 2), wn = (wave & 1) * 64;
  const int bm = blockIdx.y, bn = blockIdx.x;

  const bf16* ag = A + (bm * BM + (tid >> 2)) * K + (tid & 3) * 8;
  const bf16* bg = BT + (bn * 128 + (tid >> 2)) * K + (tid & 3) * 8;
  bf16* la = &As[tid * 8];
  bf16* lb = &Bs[tid * 8];

  f32x4 acc[MT][4] = {};

  for (int k0 = 0; k0 < K; k0 += 32) {
    async_cp16(ag + k0, la);
    if (BM == 128) async_cp16(ag + 64 * K + k0, la + 2048);
    async_cp16(bg + k0, lb);
    async_cp16(bg + 64 * K + k0, lb + 2048);
    __syncthreads();
    bf16x8 af[MT], bff[4];
#pragma unroll
    for (int t = 0; t < MT; ++t)
      af[t] = *(const bf16x8*)&As[(wm + t * 16 + l16) * 32 + quad * 8];
#pragma unroll
    for (int t = 0; t < 4; ++t)
      bff[t] = *(const bf16x8*)&Bs[(wn + t * 16 + l16) * 32 + quad * 8];
#pragma unroll
    for (int mt = 0; mt < MT; ++mt)
#pragma unroll
      for (int nt = 0; nt < 4; ++nt) acc[mt][nt] = MFMA16(af[mt], bff[nt], acc[mt][nt]);
    __syncthreads();
  }

  if (MODE == 0) {
#pragma unroll
    for (int mt = 0; mt < MT; ++mt)
#pragma unroll
      for (int i = 0; i < 4; ++i) {
        const int row = bm * BM + wm + mt * 16 + quad * 4 + i;
#pragma unroll
        for (int nt = 0; nt < 4; ++nt) {
          const int col = bn * 128 + wn + nt * 16 + l16;
          C[row * N + col] = acc[mt][nt][i];
        }
      }
  } else {
    // per-wave LDS bounce buffer (reuses Bs; safe after final barrier above)
    bf16* tb = &Bs[wave * 512];  // 16 x 16 tile, stride 20 (conflict-free)
#pragma unroll
    for (int mt = 0; mt < MT; ++mt) {
      const int s0 = bm * BM + wm + mt * 16;  // = b*2048 + sbase, 16-aligned
      const int b = s0 >> 11, sbase = s0 & 2047;
#pragma unroll
      for (int nt = 0; nt < 4; ++nt) {
        const int colb = bn * 128 + wn + nt * 16;
        const int sec = colb >> 10, rem = colb & 1023;
        const int h = rem >> 6, d0 = rem & 63;
        if (sec < 2) {  // q or k: RoPE, bounce through LDS for b64 stores
          const int d = d0 + l16;
#pragma unroll
          for (int i = 0; i < 4; ++i) {
            const int s = sbase + quad * 4 + i;
            float v = acc[mt][nt][i];
            float pr = __shfl_xor(v, 1);  // partner dim d^1 (lane l16^1)
            float rot = (d & 1) ? pr : -pr;
            float rv = v * ropeC[s * 64 + d] + rot * ropeS[s * 64 + d];
            if (sec == 0) rv *= QSC;  // fold softmax scale*log2e into q
            tb[(quad * 4 + i) * 20 + l16] = (bf16)rv;
          }
          bf16* dst = ((sec == 0) ? qws : kws) + ((b * 16 + h) * 2048 + sbase) * 64 + d0;
          bf16x4 seg = *(const bf16x4*)&tb[l16 * 20 + quad * 4];
          *(bf16x4*)(dst + l16 * 64 + quad * 4) = seg;
        } else {  // v: pack 4 consecutive s at fixed d, store b64 to vT (d-major)
          const int d = d0 + l16;
          bf16x4 pk;
#pragma unroll
          for (int i = 0; i < 4; ++i) pk[i] = (bf16)acc[mt][nt][i];
          *(bf16x4*)(vT + ((b * 16 + h) * 64 + d) * 2048 + sbase + quad * 4) = pk;
        }
      }
    }
  }
}

// ---------------- dual-triangle attention v3 ----------------
// grid: 1024 blocks = 32 (b,h) * 16 row-blocks(64 rows... see below) -- actually
// 32 bh * 32 row-blocks of 64 rows. Block = 4 waves = 2 row-groups x 2 K-halves.
// Wave (rg, kh): rows rb+rg*32 .. +32, K-cols kh*1024 .. +1024, 16 jt tiles of 64.
// jt range splits into [pure-down | mixed | pure-up]; pure tiles run one K-half
// and no per-element select. P slab double-buffered -> jt iterations overlap.
#define PSLAB (32 * 72)
__global__ __launch_bounds__(256) void attn_k(const bf16* __restrict__ qws,
                                              const bf16* __restrict__ kws,
                                              const bf16* __restrict__ vT,
                                              bf16* __restrict__ aw) {
  __shared__ __align__(16) char smem[37376];  // P: 4w*2buf*2304B=36864 | merge aliased
  const int tid = threadIdx.x;
  const int lane = tid & 63, wave = tid >> 6;
  const int l16 = lane & 15, quad = lane >> 4;
  const int bh = blockIdx.x >> 5, rb = (blockIdx.x & 31) * 64;
  const int b = bh >> 4, h = bh & 15;
  const int rg = wave & 1, kh = wave >> 1;
  const int rowbase = rb + rg * 32;
  const int base = kh * 1024;

  const bf16* qb = qws + (bh * 2048 + rowbase) * 64;
  const bf16* kb = kws + bh * 2048 * 64;
  const bf16* vbase = vT + bh * 64 * 2048;
  bf16* pw = (bf16*)smem + wave * (2 * PSLAB);

  bf16x8 qf[2][2];
#pragma unroll
  for (int mt = 0; mt < 2; ++mt)
#pragma unroll
    for (int hf = 0; hf < 2; ++hf)
      qf[mt][hf] = *(const bf16x8*)(qb + (mt * 16 + l16) * 64 + hf * 32 + quad * 8);

  f32x4 o[2][4] = {};
  float lp[2] = {0.f, 0.f};
  const f32x4 zz = {};

#define JT_BODY(TM)                                                                     \
  {                                                                                     \
    const int j0 = base + jt * 64;                                                      \
    bf16* pc = pw + (jt & 1) * PSLAB;                                                   \
    bf16x8 vf[2][4];                                                                    \
    _Pragma("unroll") for (int ks = 0; ks < 2; ++ks)                                    \
      _Pragma("unroll") for (int nt = 0; nt < 4; ++nt)                                  \
        vf[ks][nt] = *(const bf16x8*)(vbase + (nt * 16 + l16) * 2048 + j0 + ks * 32 +   \
                                      quad * 8);                                        \
    _Pragma("unroll") for (int nt = 0; nt < 4; ++nt) {                                  \
      const bf16* kp = kb + (j0 + nt * 16 + l16) * 64 + quad * 8;                       \
      f32x4 sU[2], sD[2];                                                               \
      if (TM != 0) {                                                                    \
        bf16x8 kfu = *(const bf16x8*)kp;                                                \
        _Pragma("unroll") for (int mt = 0; mt < 2; ++mt)                                \
            sU[mt] = MFMA16(kfu, qf[mt][0], zz);                                        \
      }                                                                                 \
      if (TM != 2) {                                                                    \
        bf16x8 kfd = *(const bf16x8*)(kp + 32);                                         \
        _Pragma("unroll") for (int mt = 0; mt < 2; ++mt)                                \
            sD[mt] = MFMA16(kfd, qf[mt][1], zz);                                        \
      }                                                                                 \
      _Pragma("unroll") for (int mt = 0; mt < 2; ++mt) {                                \
        bf16x4 pk;                                                                      \
        float ls = 0.f;                                                                 \
        _Pragma("unroll") for (int r = 0; r < 4; ++r) {                                 \
          float x;                                                                      \
          if (TM == 0) x = sD[mt][r];                                                   \
          else if (TM == 2) x = sU[mt][r];                                              \
          else {                                                                        \
            const int jcol = j0 + nt * 16 + quad * 4 + r;                               \
            const int irow = rowbase + mt * 16 + l16;                                   \
            x = (jcol <= irow) ? sD[mt][r] : sU[mt][r];                                 \
          }                                                                             \
          float pe = exp2f(x);                                                          \
          ls += pe;                                                                     \
          pk[r] = (bf16)pe;                                                             \
        }                                                                               \
        lp[mt] += ls;                                                                   \
        *(bf16x4*)(pc + (mt * 16 + l16) * 72 + nt * 16 + quad * 4) = pk;                \
      }                                                                                 \
    }                                                                                   \
    _Pragma("unroll") for (int mt = 0; mt < 2; ++mt)                                    \
      _Pragma("unroll") for (int ks = 0; ks < 2; ++ks) {                                \
        bf16x8 pf = *(const bf16x8*)(pc + (mt * 16 + l16) * 72 + ks * 32 + quad * 8);   \
        _Pragma("unroll") for (int nt = 0; nt < 4; ++nt)                                \
            o[mt][nt] = MFMA16(pf, vf[ks][nt], o[mt][nt]);                              \
      }                                                                                 \
  }

  int td = (rowbase - base) >> 6;               // jt < td  : tile fully below diag
  td = td < 0 ? 0 : (td > 16 ? 16 : td);
  int tu = (rowbase + 32 - base + 63) >> 6;     // jt >= tu : tile fully above diag
  tu = tu < td ? td : (tu > 16 ? 16 : tu);

#pragma unroll 2
  for (int jt = 0; jt < td; ++jt) JT_BODY(0)
  for (int jt = td; jt < tu; ++jt) JT_BODY(1)
#pragma unroll 2
  for (int jt = tu; jt < 16; ++jt) JT_BODY(2)
#undef JT_BODY

  // row-sum of l across the 4 quads (each held a j-subrange)
#pragma unroll
  for (int mt = 0; mt < 2; ++mt) {
    lp[mt] += __shfl_xor(lp[mt], 16);
    lp[mt] += __shfl_xor(lp[mt], 32);
  }
  __syncthreads();  // all P reads done before aliasing P region as merge space
  float* oL = (float*)smem;            // [4 waves][32 rows][64 cols]
  float* lL = (float*)(smem + 32768);  // [4 waves][32 rows]
#pragma unroll
  for (int mt = 0; mt < 2; ++mt) {
#pragma unroll
    for (int nt = 0; nt < 4; ++nt)
#pragma unroll
      for (int r = 0; r < 4; ++r)
        oL[wave * 2048 + (mt * 16 + quad * 4 + r) * 64 + nt * 16 + l16] = o[mt][nt][r];
    if (quad == 0) lL[wave * 32 + mt * 16 + l16] = lp[mt];
  }
  __syncthreads();
  // merge K-half pairs (rg, kh=0) + (rg, kh=1) = waves rg and rg+2
  const int c = tid & 63, w2 = tid >> 6;
#pragma unroll
  for (int rr = 0; rr < 16; ++rr) {
    const int r = w2 * 16 + rr;  // 0..63 within block
    const int rg2 = r >> 5, rloc = r & 31;
    float s2 = oL[rg2 * 2048 + rloc * 64 + c] + oL[(rg2 + 2) * 2048 + rloc * 64 + c];
    float ls = lL[rg2 * 32 + rloc] + lL[(rg2 + 2) * 32 + rloc];
    aw[(b * 2048 + rb + r) * 1024 + h * 64 + c] = (bf16)(s2 / ls);
  }
}

extern "C" void kernel_launch(void* const* d_in, const int* in_sizes, int n_in,
                              void* d_out, int out_size, void* d_ws, size_t ws_size,
                              hipStream_t stream) {
  const float* x = (const float*)d_in[0];       // (2,2048,1024) fp32
  const float* w_qkv = (const float*)d_in[1];   // (1024,3072) fp32
  const float* w_proj = (const float*)d_in[2];  // (1024,1024) fp32
  const float* ropeC = (const float*)d_in[3];   // (2048,64) fp32
  const float* ropeS = (const float*)d_in[4];   // (2048,64) fp32
  float* out = (float*)d_out;                   // (2,2048,1024) fp32

  char* ws = (char*)d_ws;
  bf16* xb = (bf16*)ws;     ws += (size_t)4194304 * 2;  // (4096,1024) bf16
  bf16* wqkvT = (bf16*)ws;  ws += (size_t)3145728 * 2;  // (3072,1024) N-major bf16
  bf16* wprojT = (bf16*)ws; ws += (size_t)1048576 * 2;  // (1024,1024) N-major bf16
  bf16* qws = (bf16*)ws;    ws += (size_t)4194304 * 2;  // (2,16,2048,64), q pre-scaled
  bf16* kws = (bf16*)ws;    ws += (size_t)4194304 * 2;  // (2,16,2048,64)
  bf16* vT = (bf16*)ws;     ws += (size_t)4194304 * 2;  // (2,16,64,2048)
  bf16* aw = (bf16*)ws;     ws += (size_t)4194304 * 2;  // (4096,1024)

  convx_k<<<1024, 256, 0, stream>>>(x, xb, 4194304);
  transpose_k<<<dim3(3072 / 64, 1024 / 64), 256, 0, stream>>>(w_qkv, wqkvT, 1024, 3072);
  transpose_k<<<dim3(1024 / 64, 1024 / 64), 256, 0, stream>>>(w_proj, wprojT, 1024, 1024);

  gemm128<1, 128><<<dim3(3072 / 128, 4096 / 128), 256, 0, stream>>>(
      xb, wqkvT, 4096, 3072, 1024, nullptr, qws, kws, vT, ropeC, ropeS);
  attn_k<<<1024, 256, 0, stream>>>(qws, kws, vT, aw);
  gemm128<0, 64><<<dim3(1024 / 128, 4096 / 64), 256, 0, stream>>>(
      aw, wprojT, 4096, 1024, 1024, out, nullptr, nullptr, nullptr, nullptr, nullptr);
}